// Round 1
// baseline (495.111 us; speedup 1.0000x reference)
//
#include <hip/hip_runtime.h>
#include <hip/hip_bf16.h>
#include <cstddef>

// Problem constants
#define BATCH 2
#define SEQ   2048
#define DM    768
#define NH    12
#define HD    64
#define N3    2304      // 3*DM
#define KSEL  46        // ceil(sqrt(2048))
#define NROW  (BATCH*KSEL)  // 92

// ---------------------------------------------------------------------------
// 1) selection prob per row: sel[r] = softmax((x@sel_w + sel_b)/T)[1]
//    one wave per row (4 waves / block)
// ---------------------------------------------------------------------------
__global__ __launch_bounds__(256) void sel_kernel(
    const float* __restrict__ x, const float* __restrict__ sel_w,
    const float* __restrict__ sel_b, const float* __restrict__ temp,
    float* __restrict__ sel) {
  int wave = threadIdx.x >> 6;
  int lane = threadIdx.x & 63;
  int row = blockIdx.x * 4 + wave;              // < 4096
  const float* xr = x + (size_t)row * DM;
  float a0 = 0.f, a1 = 0.f;
  for (int i = 0; i < DM / 64; ++i) {
    int k = lane + 64 * i;
    float xv = xr[k];
    a0 += xv * sel_w[2 * k];
    a1 += xv * sel_w[2 * k + 1];
  }
  for (int off = 32; off; off >>= 1) {
    a0 += __shfl_xor(a0, off);
    a1 += __shfl_xor(a1, off);
  }
  if (lane == 0) {
    float t = temp[0];
    float l0 = (a0 + sel_b[0]) / t;
    float l1 = (a1 + sel_b[1]) / t;
    sel[row] = 1.0f / (1.0f + expf(l0 - l1));
  }
}

// ---------------------------------------------------------------------------
// 2) top-46 per batch, tie-break lower index (matches jax.lax.top_k)
//    one block per batch
// ---------------------------------------------------------------------------
__global__ __launch_bounds__(256) void topk_kernel(
    const float* __restrict__ sel, int* __restrict__ idx) {
  __shared__ float vals[SEQ];
  __shared__ float rv[256];
  __shared__ int   ri[256];
  int b = blockIdx.x, tid = threadIdx.x;
  for (int i = tid; i < SEQ; i += 256) vals[i] = sel[b * SEQ + i];
  __syncthreads();
  for (int j = 0; j < KSEL; ++j) {
    float bv = -1e30f; int bi = 0x7fffffff;
    for (int i = tid; i < SEQ; i += 256) {
      float v = vals[i];
      if (v > bv || (v == bv && i < bi)) { bv = v; bi = i; }
    }
    rv[tid] = bv; ri[tid] = bi;
    __syncthreads();
    for (int s = 128; s; s >>= 1) {
      if (tid < s) {
        float v2 = rv[tid + s]; int i2 = ri[tid + s];
        if (v2 > rv[tid] || (v2 == rv[tid] && i2 < ri[tid])) {
          rv[tid] = v2; ri[tid] = i2;
        }
      }
      __syncthreads();
    }
    if (tid == 0) { idx[b * KSEL + j] = ri[0]; vals[ri[0]] = -1e30f; }
    __syncthreads();
  }
}

// ---------------------------------------------------------------------------
// 3) QKV GEMM: C[4096,2304] = x[4096,768] @ Wqkv[768,2304] + bias
//    64x64 tile, BK=16, 256 threads, 4x4 microtile, fp32
// ---------------------------------------------------------------------------
#define QBM 64
#define QBN 64
#define QBK 16
__global__ __launch_bounds__(256) void qkv_kernel(
    const float* __restrict__ A, const float* __restrict__ Bw,
    const float* __restrict__ bias, float* __restrict__ C) {
  __shared__ float As[QBK][QBM + 4];   // stride 68 -> 16B-aligned rows, 2-way max conflicts
  __shared__ float Bs[QBK][QBN];
  const int tid = threadIdx.x;
  const int tx = tid & 15, ty = tid >> 4;
  const int m0 = blockIdx.y * QBM, n0 = blockIdx.x * QBN;
  float acc[4][4] = {};
  for (int k0 = 0; k0 < DM; k0 += QBK) {
    {   // A tile 64x16 -> transposed into As[k][m]
      int i = tid >> 2;
      int c = (tid & 3) * 4;
      const float4 av = *(const float4*)&A[(size_t)(m0 + i) * DM + k0 + c];
      As[c + 0][i] = av.x; As[c + 1][i] = av.y;
      As[c + 2][i] = av.z; As[c + 3][i] = av.w;
    }
    {   // B tile 16x64
      int r = tid >> 4;
      int c = (tid & 15) * 4;
      *(float4*)&Bs[r][c] = *(const float4*)&Bw[(size_t)(k0 + r) * N3 + n0 + c];
    }
    __syncthreads();
#pragma unroll
    for (int kk = 0; kk < QBK; ++kk) {
      float4 a4 = *(const float4*)&As[kk][ty * 4];
      float4 b4 = *(const float4*)&Bs[kk][tx * 4];
      float a[4] = {a4.x, a4.y, a4.z, a4.w};
      float bb[4] = {b4.x, b4.y, b4.z, b4.w};
#pragma unroll
      for (int i = 0; i < 4; ++i)
#pragma unroll
        for (int j = 0; j < 4; ++j) acc[i][j] += a[i] * bb[j];
    }
    __syncthreads();
  }
#pragma unroll
  for (int i = 0; i < 4; ++i) {
    float4 o;
    o.x = acc[i][0] + bias[n0 + tx * 4 + 0];
    o.y = acc[i][1] + bias[n0 + tx * 4 + 1];
    o.z = acc[i][2] + bias[n0 + tx * 4 + 2];
    o.w = acc[i][3] + bias[n0 + tx * 4 + 3];
    *(float4*)&C[(size_t)(m0 + ty * 4 + i) * N3 + n0 + tx * 4] = o;
  }
}

// ---------------------------------------------------------------------------
// 4) attention, only for selected rows. Block = 256 threads = 4 waves;
//    wave w handles selected row j = bx*4+w of (b,h). K/V chunks (64 keys)
//    staged in LDS, shared by all 4 waves. Online softmax, fp32.
//    ctx_rows[(b*46+j)*768 + h*64 + d]
// ---------------------------------------------------------------------------
__global__ __launch_bounds__(256) void attn_kernel(
    const float* __restrict__ qkv, const int* __restrict__ idx,
    float* __restrict__ ctx_rows) {
  __shared__ float Ks[64][65];
  __shared__ float Vs[64][65];
  __shared__ float qs[4][64];
  __shared__ float ps[4][64];
  __shared__ int ts[4];
  const int tid = threadIdx.x;
  const int wave = tid >> 6, lane = tid & 63;
  const int h = blockIdx.y, b = blockIdx.z;
  const int j = blockIdx.x * 4 + wave;
  const bool valid = (j < KSEL);
  const int t = valid ? idx[b * KSEL + j] : -1;
  if (valid)
    qs[wave][lane] = qkv[((size_t)(b * SEQ + t) * 3 + 0) * DM + h * HD + lane];
  if (lane == 0) ts[wave] = t;
  __syncthreads();
  const int tmax = max(max(ts[0], ts[1]), max(ts[2], ts[3]));

  float m = -1e30f, l = 0.f, o = 0.f;
  for (int s0 = 0; s0 <= tmax; s0 += 64) {
    // stage K,V chunk: 64 keys x 64 dims each
    for (int q4 = tid; q4 < 1024; q4 += 256) {
      int r = q4 >> 4, c = (q4 & 15) * 4;
      const float4 kv = *(const float4*)&qkv[((size_t)(b * SEQ + s0 + r) * 3 + 1) * DM + h * HD + c];
      Ks[r][c] = kv.x; Ks[r][c + 1] = kv.y; Ks[r][c + 2] = kv.z; Ks[r][c + 3] = kv.w;
      const float4 vv = *(const float4*)&qkv[((size_t)(b * SEQ + s0 + r) * 3 + 2) * DM + h * HD + c];
      Vs[r][c] = vv.x; Vs[r][c + 1] = vv.y; Vs[r][c + 2] = vv.z; Vs[r][c + 3] = vv.w;
    }
    __syncthreads();
    // score for key s = s0 + lane
    float sc = 0.f;
#pragma unroll
    for (int d = 0; d < 64; ++d) sc += qs[wave][d] * Ks[lane][d];
    sc *= 0.125f;                       // 1/sqrt(64)
    if (s0 + lane > t) sc = -1e30f;     // causal mask (and invalid rows)
    float cm = sc;
    for (int off = 32; off; off >>= 1) cm = fmaxf(cm, __shfl_xor(cm, off));
    float mn = fmaxf(m, cm);
    float alpha = __expf(m - mn);
    float p = __expf(sc - mn);
    float sp = p;
    for (int off = 32; off; off >>= 1) sp += __shfl_xor(sp, off);
    l = l * alpha + sp;
    ps[wave][lane] = p;
    __syncthreads();
    float oacc = 0.f;
#pragma unroll
    for (int s = 0; s < 64; ++s) oacc += ps[wave][s] * Vs[s][lane];
    o = o * alpha + oacc;
    m = mn;
    __syncthreads();   // before next chunk overwrites Ks/Vs
  }
  if (valid)
    ctx_rows[((size_t)(b * KSEL + j) * NH + h) * HD + lane] = o / l;
}

// ---------------------------------------------------------------------------
// 5) out-proj + gate for the 92 selected rows:
//    gated_rows[row] = (ctx_rows[row] @ out_w + out_b) * sel[b,t]
// ---------------------------------------------------------------------------
__global__ __launch_bounds__(256) void outproj_kernel(
    const float* __restrict__ ctx_rows, const float* __restrict__ Wo,
    const float* __restrict__ ob, const int* __restrict__ idx,
    const float* __restrict__ sel, float* __restrict__ gated_rows) {
  __shared__ float cs[DM];
  const int row = blockIdx.x;           // 0..91
  const int b = row / KSEL;
  const int t = idx[row];
  const int tid = threadIdx.x;
  for (int i = tid; i < DM; i += 256) cs[i] = ctx_rows[(size_t)row * DM + i];
  __syncthreads();
  float a0 = 0.f, a1 = 0.f, a2 = 0.f;
  for (int k = 0; k < DM; ++k) {
    float c = cs[k];
    const float* wr = &Wo[(size_t)k * DM];
    a0 += c * wr[tid];
    a1 += c * wr[tid + 256];
    a2 += c * wr[tid + 512];
  }
  float sv = sel[b * SEQ + t];
  gated_rows[(size_t)row * DM + tid      ] = (a0 + ob[tid      ]) * sv;
  gated_rows[(size_t)row * DM + tid + 256] = (a1 + ob[tid + 256]) * sv;
  gated_rows[(size_t)row * DM + tid + 512] = (a2 + ob[tid + 512]) * sv;
}

// ---------------------------------------------------------------------------
// 6) y = x  (float4 copy)
// ---------------------------------------------------------------------------
__global__ __launch_bounds__(256) void copy_kernel(
    const float* __restrict__ x, float* __restrict__ y) {
  int i = blockIdx.x * 256 + threadIdx.x;   // n4 = 786432 exactly
  ((float4*)y)[i] = ((const float4*)x)[i];
}

// ---------------------------------------------------------------------------
// 7) y[b, idx[row], :] += gated_rows[row, :]   (indices unique per batch)
// ---------------------------------------------------------------------------
__global__ void scatter_kernel(
    const float* __restrict__ gated_rows, const int* __restrict__ idx,
    float* __restrict__ y) {
  const int row = blockIdx.x;   // 0..91
  const int b = row / KSEL;
  const int t = idx[row];
  const int c = threadIdx.x * 4;  // 192 threads
  float4 g = *(const float4*)&gated_rows[(size_t)row * DM + c];
  float4* yp = (float4*)&y[(size_t)(b * SEQ + t) * DM + c];
  float4 v = *yp;
  v.x += g.x; v.y += g.y; v.z += g.z; v.w += g.w;
  *yp = v;
}

// ---------------------------------------------------------------------------
extern "C" void kernel_launch(void* const* d_in, const int* in_sizes, int n_in,
                              void* d_out, int out_size, void* d_ws, size_t ws_size,
                              hipStream_t stream) {
  const float* x      = (const float*)d_in[0];
  const float* Wqkv_w = (const float*)d_in[1];
  const float* Wqkv_b = (const float*)d_in[2];
  const float* sel_w  = (const float*)d_in[3];
  const float* sel_b  = (const float*)d_in[4];
  const float* out_w  = (const float*)d_in[5];
  const float* out_b  = (const float*)d_in[6];
  const float* temp   = (const float*)d_in[7];
  float* y = (float*)d_out;

  // workspace layout (floats)
  float* ws = (float*)d_ws;
  float* qkv        = ws;                                  // 4096*2304
  float* sel        = qkv + (size_t)BATCH * SEQ * N3;      // 4096
  int*   idx        = (int*)(sel + BATCH * SEQ);           // 92 (pad 128)
  float* ctx_rows   = (float*)(idx + 128);                 // 92*768
  float* gated_rows = ctx_rows + (size_t)NROW * DM;        // 92*768

  sel_kernel<<<dim3(BATCH * SEQ / 4), 256, 0, stream>>>(x, sel_w, sel_b, temp, sel);
  topk_kernel<<<dim3(BATCH), 256, 0, stream>>>(sel, idx);
  qkv_kernel<<<dim3(N3 / QBN, BATCH * SEQ / QBM), 256, 0, stream>>>(x, Wqkv_w, Wqkv_b, qkv);
  attn_kernel<<<dim3((KSEL + 3) / 4, NH, BATCH), 256, 0, stream>>>(qkv, idx, ctx_rows);
  outproj_kernel<<<dim3(NROW), 256, 0, stream>>>(ctx_rows, out_w, out_b, idx, sel, gated_rows);
  copy_kernel<<<dim3(BATCH * SEQ * DM / 4 / 256), 256, 0, stream>>>(x, y);
  scatter_kernel<<<dim3(NROW), 192, 0, stream>>>(gated_rows, idx, y);
}

// Round 2
// 376.380 us; speedup vs baseline: 1.3155x; 1.3155x over previous
//
#include <hip/hip_runtime.h>
#include <hip/hip_bf16.h>
#include <cstddef>

// Problem constants
#define BATCH 2
#define SEQ   2048
#define DM    768
#define NH    12
#define HD    64
#define N3    2304      // 3*DM
#define NKV   1536      // 2*DM (K,V cols)
#define KSEL  46        // ceil(sqrt(2048))
#define NROW  (BATCH*KSEL)  // 92

typedef unsigned short ushort_t;
typedef __attribute__((ext_vector_type(8))) short bf16x8;
typedef __attribute__((ext_vector_type(4))) float f32x4;

__device__ __forceinline__ ushort_t f2bf(float f) {
  __hip_bfloat16 h = __float2bfloat16(f);
  union { __hip_bfloat16 h; ushort_t u; } cv; cv.h = h;
  return cv.u;
}

#define GLD16(g, l)                                                         \
  __builtin_amdgcn_global_load_lds(                                         \
      (const __attribute__((address_space(1))) void*)(g),                   \
      (__attribute__((address_space(3))) void*)(l), 16, 0, 0)

// ---------------------------------------------------------------------------
// cast x fp32 -> bf16 (row-major unchanged)
// ---------------------------------------------------------------------------
__global__ __launch_bounds__(256) void cast_x_kernel(
    const float* __restrict__ x, ushort_t* __restrict__ xb) {
  int i = blockIdx.x * 256 + threadIdx.x;   // 3072 blocks * 256 * 4 elems
  float4 f = ((const float4*)x)[i];
  ushort4 o;
  o.x = f2bf(f.x); o.y = f2bf(f.y); o.z = f2bf(f.z); o.w = f2bf(f.w);
  ((ushort4*)xb)[i] = o;
}

// ---------------------------------------------------------------------------
// transpose-cast Wqkv cols 768..2303 : Wt[n][k] = bf16(W[k][768+n])
// 32x32 tiles; grid (48, 24)
// ---------------------------------------------------------------------------
__global__ __launch_bounds__(256) void wt_kernel(
    const float* __restrict__ W, ushort_t* __restrict__ Wt) {
  __shared__ float tile[32][33];
  const int n0 = blockIdx.x * 32, k0 = blockIdx.y * 32;
  const int tid = threadIdx.x;
  const int r = tid >> 3, c4 = (tid & 7) * 4;
  float4 f = *(const float4*)&W[(size_t)(k0 + r) * N3 + DM + n0 + c4];
  tile[r][c4] = f.x; tile[r][c4 + 1] = f.y; tile[r][c4 + 2] = f.z; tile[r][c4 + 3] = f.w;
  __syncthreads();
  ushort4 o;
  o.x = f2bf(tile[c4 + 0][r]);
  o.y = f2bf(tile[c4 + 1][r]);
  o.z = f2bf(tile[c4 + 2][r]);
  o.w = f2bf(tile[c4 + 3][r]);
  *(ushort4*)&Wt[(size_t)(n0 + r) * DM + k0 + c4] = o;
}

// ---------------------------------------------------------------------------
// selection prob per row (fp32, bit-identical to R1 so topk can't flip)
// ---------------------------------------------------------------------------
__global__ __launch_bounds__(256) void sel_kernel(
    const float* __restrict__ x, const float* __restrict__ sel_w,
    const float* __restrict__ sel_b, const float* __restrict__ temp,
    float* __restrict__ sel) {
  int wave = threadIdx.x >> 6;
  int lane = threadIdx.x & 63;
  int row = blockIdx.x * 4 + wave;              // < 4096
  const float* xr = x + (size_t)row * DM;
  float a0 = 0.f, a1 = 0.f;
  for (int i = 0; i < DM / 64; ++i) {
    int k = lane + 64 * i;
    float xv = xr[k];
    a0 += xv * sel_w[2 * k];
    a1 += xv * sel_w[2 * k + 1];
  }
  for (int off = 32; off; off >>= 1) {
    a0 += __shfl_xor(a0, off);
    a1 += __shfl_xor(a1, off);
  }
  if (lane == 0) {
    float t = temp[0];
    float l0 = (a0 + sel_b[0]) / t;
    float l1 = (a1 + sel_b[1]) / t;
    sel[row] = 1.0f / (1.0f + expf(l0 - l1));
  }
}

// ---------------------------------------------------------------------------
// top-46 per batch: ONE WAVE per batch, values in registers, no barriers.
// tie-break lower index (matches jax.lax.top_k)
// ---------------------------------------------------------------------------
__global__ __launch_bounds__(64) void topk_kernel(
    const float* __restrict__ sel, int* __restrict__ idx) {
  const int b = blockIdx.x, lane = threadIdx.x;
  float v[32];
#pragma unroll
  for (int e = 0; e < 32; ++e) v[e] = sel[b * SEQ + e * 64 + lane];
  for (int j = 0; j < KSEL; ++j) {
    float bv = -1e30f; int bi = 0x7fffffff;
#pragma unroll
    for (int e = 0; e < 32; ++e) {
      int gi = e * 64 + lane;
      if (v[e] > bv || (v[e] == bv && gi < bi)) { bv = v[e]; bi = gi; }
    }
#pragma unroll
    for (int off = 32; off; off >>= 1) {
      float ov = __shfl_xor(bv, off);
      int oi = __shfl_xor(bi, off);
      if (ov > bv || (ov == bv && oi < bi)) { bv = ov; bi = oi; }
    }
    if (lane == 0) idx[b * KSEL + j] = bi;
#pragma unroll
    for (int e = 0; e < 32; ++e)
      if (e * 64 + lane == bi) v[e] = -1e30f;
  }
}

// ---------------------------------------------------------------------------
// KV GEMM (bf16 MFMA): C[4096,1536] = Xbf[4096,768] @ Wt^T + bias
// 128x128 tile, BK=32, 4 waves each 64x64 (4x4 of 16x16x32 MFMA)
// global_load_lds width=16 staging. grid (12, 32)
// ---------------------------------------------------------------------------
__global__ __launch_bounds__(256) void kv_gemm(
    const ushort_t* __restrict__ Xbf,   // [4096][768]
    const ushort_t* __restrict__ Wt,    // [1536][768]
    const float* __restrict__ bias,     // 1536 (Wqkv_b + 768)
    float* __restrict__ C) {            // [4096][1536]
  __shared__ ushort_t As[128 * 32];
  __shared__ ushort_t Bs[128 * 32];
  const int tid = threadIdx.x;
  const int lane = tid & 63, w = tid >> 6;
  const int wr = w >> 1, wc = w & 1;
  const int m0 = blockIdx.y * 128, n0 = blockIdx.x * 128;
  const int quad = lane >> 4, l16 = lane & 15;
  const int ci0 = tid;        // chunk ids (16B each), pass 0
  const int ci1 = 256 + tid;  // pass 1
  f32x4 acc[4][4] = {};
  for (int k0 = 0; k0 < DM; k0 += 32) {
    GLD16(Xbf + (size_t)(m0 + (ci0 >> 2)) * DM + k0 + (ci0 & 3) * 8, &As[(w * 64) * 8]);
    GLD16(Xbf + (size_t)(m0 + (ci1 >> 2)) * DM + k0 + (ci1 & 3) * 8, &As[(256 + w * 64) * 8]);
    GLD16(Wt  + (size_t)(n0 + (ci0 >> 2)) * DM + k0 + (ci0 & 3) * 8, &Bs[(w * 64) * 8]);
    GLD16(Wt  + (size_t)(n0 + (ci1 >> 2)) * DM + k0 + (ci1 & 3) * 8, &Bs[(256 + w * 64) * 8]);
    __syncthreads();
    bf16x8 af[4], bfr[4];
#pragma unroll
    for (int i = 0; i < 4; ++i)
      af[i] = *(const bf16x8*)&As[(wr * 64 + i * 16 + l16) * 32 + quad * 8];
#pragma unroll
    for (int j = 0; j < 4; ++j)
      bfr[j] = *(const bf16x8*)&Bs[(wc * 64 + j * 16 + l16) * 32 + quad * 8];
#pragma unroll
    for (int i = 0; i < 4; ++i)
#pragma unroll
      for (int j = 0; j < 4; ++j)
        acc[i][j] = __builtin_amdgcn_mfma_f32_16x16x32_bf16(af[i], bfr[j], acc[i][j], 0, 0, 0);
    __syncthreads();
  }
#pragma unroll
  for (int i = 0; i < 4; ++i) {
    const int row_base = m0 + wr * 64 + i * 16 + quad * 4;
#pragma unroll
    for (int j = 0; j < 4; ++j) {
      const int col = n0 + wc * 64 + j * 16 + l16;
      const float bv = bias[col];
#pragma unroll
      for (int r = 0; r < 4; ++r)
        C[(size_t)(row_base + r) * NKV + col] = acc[i][j][r] + bv;
    }
  }
}

// ---------------------------------------------------------------------------
// Q for the 92 selected rows (fp32): q_rows[row] = x[b,t] @ Wqkv[:, :768] + b
// one block per row
// ---------------------------------------------------------------------------
__global__ __launch_bounds__(256) void qrows_kernel(
    const float* __restrict__ x, const float* __restrict__ W,
    const float* __restrict__ Wb, const int* __restrict__ idx,
    float* __restrict__ q_rows) {
  __shared__ float xs[DM];
  const int row = blockIdx.x;           // 0..91
  const int b = row / KSEL;
  const int t = idx[row];
  const int tid = threadIdx.x;
  for (int i = tid; i < DM; i += 256) xs[i] = x[(size_t)(b * SEQ + t) * DM + i];
  __syncthreads();
  float a0 = 0.f, a1 = 0.f, a2 = 0.f;
  for (int k = 0; k < DM; ++k) {
    float c = xs[k];
    const float* wr = &W[(size_t)k * N3];
    a0 += c * wr[tid];
    a1 += c * wr[tid + 256];
    a2 += c * wr[tid + 512];
  }
  q_rows[(size_t)row * DM + tid      ] = a0 + Wb[tid      ];
  q_rows[(size_t)row * DM + tid + 256] = a1 + Wb[tid + 256];
  q_rows[(size_t)row * DM + tid + 512] = a2 + Wb[tid + 512];
}

// ---------------------------------------------------------------------------
// attention for selected rows; K/V from kv[4096][2][768] fp32
// ---------------------------------------------------------------------------
__global__ __launch_bounds__(256) void attn_kernel(
    const float* __restrict__ kv, const float* __restrict__ q_rows,
    const int* __restrict__ idx, float* __restrict__ ctx_rows) {
  __shared__ float Ks[64][65];
  __shared__ float Vs[64][65];
  __shared__ float qs[4][64];
  __shared__ float ps[4][64];
  __shared__ int ts[4];
  const int tid = threadIdx.x;
  const int wave = tid >> 6, lane = tid & 63;
  const int h = blockIdx.y, b = blockIdx.z;
  const int j = blockIdx.x * 4 + wave;
  const bool valid = (j < KSEL);
  const int t = valid ? idx[b * KSEL + j] : -1;
  if (valid)
    qs[wave][lane] = q_rows[(size_t)(b * KSEL + j) * DM + h * HD + lane];
  if (lane == 0) ts[wave] = t;
  __syncthreads();
  const int tmax = max(max(ts[0], ts[1]), max(ts[2], ts[3]));

  float m = -1e30f, l = 0.f, o = 0.f;
  for (int s0 = 0; s0 <= tmax; s0 += 64) {
    for (int q4 = tid; q4 < 1024; q4 += 256) {
      int r = q4 >> 4, c = (q4 & 15) * 4;
      const size_t base = (size_t)(b * SEQ + s0 + r) * NKV + h * HD + c;
      const float4 kvv = *(const float4*)&kv[base];
      Ks[r][c] = kvv.x; Ks[r][c + 1] = kvv.y; Ks[r][c + 2] = kvv.z; Ks[r][c + 3] = kvv.w;
      const float4 vv = *(const float4*)&kv[base + DM];
      Vs[r][c] = vv.x; Vs[r][c + 1] = vv.y; Vs[r][c + 2] = vv.z; Vs[r][c + 3] = vv.w;
    }
    __syncthreads();
    float sc = 0.f;
#pragma unroll
    for (int d = 0; d < 64; ++d) sc += qs[wave][d] * Ks[lane][d];
    sc *= 0.125f;                       // 1/sqrt(64)
    if (s0 + lane > t) sc = -1e30f;     // causal mask (and invalid rows)
    float cm = sc;
    for (int off = 32; off; off >>= 1) cm = fmaxf(cm, __shfl_xor(cm, off));
    float mn = fmaxf(m, cm);
    float alpha = __expf(m - mn);
    float p = __expf(sc - mn);
    float sp = p;
    for (int off = 32; off; off >>= 1) sp += __shfl_xor(sp, off);
    l = l * alpha + sp;
    ps[wave][lane] = p;
    __syncthreads();
    float oacc = 0.f;
#pragma unroll
    for (int s = 0; s < 64; ++s) oacc += ps[wave][s] * Vs[s][lane];
    o = o * alpha + oacc;
    m = mn;
    __syncthreads();
  }
  if (valid)
    ctx_rows[((size_t)(b * KSEL + j) * NH + h) * HD + lane] = o / l;
}

// ---------------------------------------------------------------------------
// out-proj + gate for the 92 selected rows
// ---------------------------------------------------------------------------
__global__ __launch_bounds__(256) void outproj_kernel(
    const float* __restrict__ ctx_rows, const float* __restrict__ Wo,
    const float* __restrict__ ob, const int* __restrict__ idx,
    const float* __restrict__ sel, float* __restrict__ gated_rows) {
  __shared__ float cs[DM];
  const int row = blockIdx.x;           // 0..91
  const int b = row / KSEL;
  const int t = idx[row];
  const int tid = threadIdx.x;
  for (int i = tid; i < DM; i += 256) cs[i] = ctx_rows[(size_t)row * DM + i];
  __syncthreads();
  float a0 = 0.f, a1 = 0.f, a2 = 0.f;
  for (int k = 0; k < DM; ++k) {
    float c = cs[k];
    const float* wr = &Wo[(size_t)k * DM];
    a0 += c * wr[tid];
    a1 += c * wr[tid + 256];
    a2 += c * wr[tid + 512];
  }
  float sv = sel[b * SEQ + t];
  gated_rows[(size_t)row * DM + tid      ] = (a0 + ob[tid      ]) * sv;
  gated_rows[(size_t)row * DM + tid + 256] = (a1 + ob[tid + 256]) * sv;
  gated_rows[(size_t)row * DM + tid + 512] = (a2 + ob[tid + 512]) * sv;
}

// ---------------------------------------------------------------------------
// y = x  (float4 copy)
// ---------------------------------------------------------------------------
__global__ __launch_bounds__(256) void copy_kernel(
    const float* __restrict__ x, float* __restrict__ y) {
  int i = blockIdx.x * 256 + threadIdx.x;   // n4 = 786432 exactly
  ((float4*)y)[i] = ((const float4*)x)[i];
}

// ---------------------------------------------------------------------------
// y[b, idx[row], :] += gated_rows[row, :]
// ---------------------------------------------------------------------------
__global__ void scatter_kernel(
    const float* __restrict__ gated_rows, const int* __restrict__ idx,
    float* __restrict__ y) {
  const int row = blockIdx.x;   // 0..91
  const int b = row / KSEL;
  const int t = idx[row];
  const int c = threadIdx.x * 4;  // 192 threads
  float4 g = *(const float4*)&gated_rows[(size_t)row * DM + c];
  float4* yp = (float4*)&y[(size_t)(b * SEQ + t) * DM + c];
  float4 v = *yp;
  v.x += g.x; v.y += g.y; v.z += g.z; v.w += g.w;
  *yp = v;
}

// ---------------------------------------------------------------------------
extern "C" void kernel_launch(void* const* d_in, const int* in_sizes, int n_in,
                              void* d_out, int out_size, void* d_ws, size_t ws_size,
                              hipStream_t stream) {
  const float* x      = (const float*)d_in[0];
  const float* Wqkv_w = (const float*)d_in[1];
  const float* Wqkv_b = (const float*)d_in[2];
  const float* sel_w  = (const float*)d_in[3];
  const float* sel_b  = (const float*)d_in[4];
  const float* out_w  = (const float*)d_in[5];
  const float* out_b  = (const float*)d_in[6];
  const float* temp   = (const float*)d_in[7];
  float* y = (float*)d_out;

  // workspace layout (floats)
  float* ws = (float*)d_ws;
  float*    kv         = ws;                                   // 4096*1536 fl
  float*    sel        = kv + (size_t)BATCH * SEQ * NKV;       // 4096
  int*      idx        = (int*)(sel + BATCH * SEQ);            // 92 (pad 128)
  float*    ctx_rows   = (float*)(idx + 128);                  // 92*768
  float*    gated_rows = ctx_rows + (size_t)NROW * DM;         // 92*768
  float*    q_rows     = gated_rows + (size_t)NROW * DM;       // 92*768
  ushort_t* Xbf        = (ushort_t*)(q_rows + (size_t)NROW * DM); // 4096*768 bf16
  ushort_t* Wt         = Xbf + (size_t)BATCH * SEQ * DM;          // 1536*768 bf16

  cast_x_kernel<<<dim3(BATCH * SEQ * DM / 4 / 256), 256, 0, stream>>>(x, Xbf);
  wt_kernel<<<dim3(NKV / 32, DM / 32), 256, 0, stream>>>(Wqkv_w, Wt);
  sel_kernel<<<dim3(BATCH * SEQ / 4), 256, 0, stream>>>(x, sel_w, sel_b, temp, sel);
  topk_kernel<<<dim3(BATCH), 64, 0, stream>>>(sel, idx);
  kv_gemm<<<dim3(NKV / 128, BATCH * SEQ / 128), 256, 0, stream>>>(Xbf, Wt, Wqkv_b + DM, kv);
  qrows_kernel<<<dim3(NROW), 256, 0, stream>>>(x, Wqkv_w, Wqkv_b, idx, q_rows);
  attn_kernel<<<dim3((KSEL + 3) / 4, NH, BATCH), 256, 0, stream>>>(kv, q_rows, idx, ctx_rows);
  outproj_kernel<<<dim3(NROW), 256, 0, stream>>>(ctx_rows, out_w, out_b, idx, sel, gated_rows);
  copy_kernel<<<dim3(BATCH * SEQ * DM / 4 / 256), 256, 0, stream>>>(x, y);
  scatter_kernel<<<dim3(NROW), 192, 0, stream>>>(gated_rows, idx, y);
}

// Round 3
// 289.216 us; speedup vs baseline: 1.7119x; 1.3014x over previous
//
#include <hip/hip_runtime.h>
#include <hip/hip_bf16.h>
#include <cstddef>

// Problem constants
#define BATCH 2
#define SEQ   2048
#define DM    768
#define NH    12
#define HD    64
#define N3    2304      // 3*DM
#define NKV   1536      // 2*DM (K,V cols)
#define KSEL  46        // ceil(sqrt(2048))
#define NROW  (BATCH*KSEL)  // 92
#define NCHUNK 32       // 2048/64

typedef unsigned short ushort_t;
typedef __attribute__((ext_vector_type(8))) short bf16x8;
typedef __attribute__((ext_vector_type(4))) float f32x4;

__device__ __forceinline__ ushort_t f2bf(float f) {
  union { __hip_bfloat16 h; ushort_t u; } cv;
  cv.h = __float2bfloat16(f);
  return cv.u;
}

#define GLD16(g, l)                                                         \
  __builtin_amdgcn_global_load_lds(                                         \
      (const __attribute__((address_space(1))) void*)(g),                   \
      (__attribute__((address_space(3))) void*)(l), 16, 0, 0)

// ---------------------------------------------------------------------------
// prep: fused cast_x (3072 blocks) + Wt transpose-cast (1152) + sel (1024)
//       + copy y=x (3072).  All independent.
// ---------------------------------------------------------------------------
__global__ __launch_bounds__(256) void prep_kernel(
    const float* __restrict__ x, const float* __restrict__ W,
    const float* __restrict__ sel_w, const float* __restrict__ sel_b,
    const float* __restrict__ temp,
    ushort_t* __restrict__ xb, ushort_t* __restrict__ Wt,
    float* __restrict__ sel, float* __restrict__ y) {
  const int bx = blockIdx.x;
  const int tid = threadIdx.x;
  if (bx < 3072) {
    // cast x -> bf16
    int i = bx * 256 + tid;
    float4 f = ((const float4*)x)[i];
    ushort4 o;
    o.x = f2bf(f.x); o.y = f2bf(f.y); o.z = f2bf(f.z); o.w = f2bf(f.w);
    ((ushort4*)xb)[i] = o;
  } else if (bx < 4224) {
    // Wt[n][k] = bf16(W[k][768+n]), 32x32 tiles
    __shared__ float tile[32][33];
    const int bx2 = bx - 3072;
    const int n0 = (bx2 % 48) * 32, k0 = (bx2 / 48) * 32;
    const int r = tid >> 3, c4 = (tid & 7) * 4;
    float4 f = *(const float4*)&W[(size_t)(k0 + r) * N3 + DM + n0 + c4];
    tile[r][c4] = f.x; tile[r][c4 + 1] = f.y; tile[r][c4 + 2] = f.z; tile[r][c4 + 3] = f.w;
    __syncthreads();
    ushort4 o;
    o.x = f2bf(tile[c4 + 0][r]);
    o.y = f2bf(tile[c4 + 1][r]);
    o.z = f2bf(tile[c4 + 2][r]);
    o.w = f2bf(tile[c4 + 3][r]);
    *(ushort4*)&Wt[(size_t)(n0 + r) * DM + k0 + c4] = o;
  } else if (bx < 5248) {
    // selection prob (fp32, bit-identical across rounds so topk stable)
    int wave = tid >> 6, lane = tid & 63;
    int row = (bx - 4224) * 4 + wave;
    const float* xr = x + (size_t)row * DM;
    float a0 = 0.f, a1 = 0.f;
    for (int i = 0; i < DM / 64; ++i) {
      int k = lane + 64 * i;
      float xv = xr[k];
      a0 += xv * sel_w[2 * k];
      a1 += xv * sel_w[2 * k + 1];
    }
    for (int off = 32; off; off >>= 1) {
      a0 += __shfl_xor(a0, off);
      a1 += __shfl_xor(a1, off);
    }
    if (lane == 0) {
      float t = temp[0];
      float l0 = (a0 + sel_b[0]) / t;
      float l1 = (a1 + sel_b[1]) / t;
      sel[row] = 1.0f / (1.0f + expf(l0 - l1));
    }
  } else {
    // y = x
    int i = (bx - 5248) * 256 + tid;
    ((float4*)y)[i] = ((const float4*)x)[i];
  }
}

// ---------------------------------------------------------------------------
// top-46 per batch: one wave per batch, values in registers, no barriers.
// ---------------------------------------------------------------------------
__global__ __launch_bounds__(64) void topk_kernel(
    const float* __restrict__ sel, int* __restrict__ idx) {
  const int b = blockIdx.x, lane = threadIdx.x;
  float v[32];
#pragma unroll
  for (int e = 0; e < 32; ++e) v[e] = sel[b * SEQ + e * 64 + lane];
  for (int j = 0; j < KSEL; ++j) {
    float bv = -1e30f; int bi = 0x7fffffff;
#pragma unroll
    for (int e = 0; e < 32; ++e) {
      int gi = e * 64 + lane;
      if (v[e] > bv || (v[e] == bv && gi < bi)) { bv = v[e]; bi = gi; }
    }
#pragma unroll
    for (int off = 32; off; off >>= 1) {
      float ov = __shfl_xor(bv, off);
      int oi = __shfl_xor(bi, off);
      if (ov > bv || (ov == bv && oi < bi)) { bv = ov; bi = oi; }
    }
    if (lane == 0) idx[b * KSEL + j] = bi;
#pragma unroll
    for (int e = 0; e < 32; ++e)
      if (e * 64 + lane == bi) v[e] = -1e30f;
  }
}

// ---------------------------------------------------------------------------
// KV GEMM (bf16 MFMA): kv[4096,1536](bf16) = Xbf @ Wt^T + bias
// 128x128 tile, BK=32, 4 waves each 64x64.  grid (12, 32)
// ---------------------------------------------------------------------------
__global__ __launch_bounds__(256) void kv_gemm(
    const ushort_t* __restrict__ Xbf,   // [4096][768]
    const ushort_t* __restrict__ Wt,    // [1536][768]
    const float* __restrict__ bias,     // 1536 (Wqkv_b + 768)
    ushort_t* __restrict__ Ckv) {       // [4096][1536] bf16
  __shared__ ushort_t As[128 * 32];
  __shared__ ushort_t Bs[128 * 32];
  const int tid = threadIdx.x;
  const int lane = tid & 63, w = tid >> 6;
  const int wr = w >> 1, wc = w & 1;
  const int m0 = blockIdx.y * 128, n0 = blockIdx.x * 128;
  const int quad = lane >> 4, l16 = lane & 15;
  const int ci0 = tid;
  const int ci1 = 256 + tid;
  f32x4 acc[4][4] = {};
  for (int k0 = 0; k0 < DM; k0 += 32) {
    GLD16(Xbf + (size_t)(m0 + (ci0 >> 2)) * DM + k0 + (ci0 & 3) * 8, &As[(w * 64) * 8]);
    GLD16(Xbf + (size_t)(m0 + (ci1 >> 2)) * DM + k0 + (ci1 & 3) * 8, &As[(256 + w * 64) * 8]);
    GLD16(Wt  + (size_t)(n0 + (ci0 >> 2)) * DM + k0 + (ci0 & 3) * 8, &Bs[(w * 64) * 8]);
    GLD16(Wt  + (size_t)(n0 + (ci1 >> 2)) * DM + k0 + (ci1 & 3) * 8, &Bs[(256 + w * 64) * 8]);
    __syncthreads();
    bf16x8 af[4], bfr[4];
#pragma unroll
    for (int i = 0; i < 4; ++i)
      af[i] = *(const bf16x8*)&As[(wr * 64 + i * 16 + l16) * 32 + quad * 8];
#pragma unroll
    for (int j = 0; j < 4; ++j)
      bfr[j] = *(const bf16x8*)&Bs[(wc * 64 + j * 16 + l16) * 32 + quad * 8];
#pragma unroll
    for (int i = 0; i < 4; ++i)
#pragma unroll
      for (int j = 0; j < 4; ++j)
        acc[i][j] = __builtin_amdgcn_mfma_f32_16x16x32_bf16(af[i], bfr[j], acc[i][j], 0, 0, 0);
    __syncthreads();
  }
#pragma unroll
  for (int i = 0; i < 4; ++i) {
    const int row_base = m0 + wr * 64 + i * 16 + quad * 4;
#pragma unroll
    for (int j = 0; j < 4; ++j) {
      const int col = n0 + wc * 64 + j * 16 + l16;
      const float bv = bias[col];
#pragma unroll
      for (int r = 0; r < 4; ++r)
        Ckv[(size_t)(row_base + r) * NKV + col] = f2bf(acc[i][j][r] + bv);
    }
  }
}

// ---------------------------------------------------------------------------
// Q for selected rows -> bf16, padded to 64 rows/batch (zeros beyond 46)
// ---------------------------------------------------------------------------
__global__ __launch_bounds__(256) void qrows_kernel(
    const float* __restrict__ x, const float* __restrict__ W,
    const float* __restrict__ Wb, const int* __restrict__ idx,
    ushort_t* __restrict__ qb) {
  const int row = blockIdx.x;           // 0..127 = b*64+j
  const int b = row >> 6, j = row & 63;
  const int tid = threadIdx.x;
  if (j >= KSEL) {
    for (int i = tid; i < DM; i += 256) qb[(size_t)row * DM + i] = 0;
    return;
  }
  __shared__ float xs[DM];
  const int t = idx[b * KSEL + j];
  for (int i = tid; i < DM; i += 256) xs[i] = x[(size_t)(b * SEQ + t) * DM + i];
  __syncthreads();
  float a0 = 0.f, a1 = 0.f, a2 = 0.f;
  for (int k = 0; k < DM; ++k) {
    float c = xs[k];
    const float* wr = &W[(size_t)k * N3];
    a0 += c * wr[tid];
    a1 += c * wr[tid + 256];
    a2 += c * wr[tid + 512];
  }
  qb[(size_t)row * DM + tid      ] = f2bf(a0 + Wb[tid      ]);
  qb[(size_t)row * DM + tid + 256] = f2bf(a1 + Wb[tid + 256]);
  qb[(size_t)row * DM + tid + 512] = f2bf(a2 + Wb[tid + 512]);
}

// ---------------------------------------------------------------------------
// attention chunk kernel: grid (32 chunks, 12 h, 2 b), 256 thr = 4 waves.
// Block computes S[64 rows x 64 keys] via MFMA, per-chunk softmax, PV via
// MFMA, writes partial (m,l,O).  Wave w owns rows 16w..16w+15.
// ---------------------------------------------------------------------------
__global__ __launch_bounds__(256) void attn_chunk_kernel(
    const ushort_t* __restrict__ kv,   // [4096][1536] bf16 (K @ h*64, V @ 768+h*64)
    const ushort_t* __restrict__ qb,   // [128][768] bf16
    const int* __restrict__ idx,
    float* __restrict__ m_part, float* __restrict__ l_part,
    float* __restrict__ o_part) {
  __shared__ __align__(16) ushort_t Vt[64][72];
  __shared__ __align__(16) ushort_t Ps[4][16][72];
  __shared__ int tS[64];
  __shared__ int tmaxS;
  const int tid = threadIdx.x;
  const int c = blockIdx.x, h = blockIdx.y, b = blockIdx.z;
  const int c0 = c * 64;
  if (tid < 64) {
    int t = (tid < KSEL) ? idx[b * KSEL + tid] : -1;
    tS[tid] = t;
    int tm = t;
    for (int off = 32; off; off >>= 1) tm = max(tm, __shfl_xor(tm, off));
    if (tid == 0) tmaxS = tm;
  }
  __syncthreads();
  if (c0 > tmaxS) return;   // uniform across block

  // stage V transposed: Vt[d][key]
  {
    const int key = tid >> 2, ds0 = (tid & 3) * 16;
    const ushort_t* vsrc = kv + (size_t)(b * SEQ + c0 + key) * NKV + DM + h * HD + ds0;
    ushort_t tmp[16];
    *(uint4*)&tmp[0] = *(const uint4*)&vsrc[0];
    *(uint4*)&tmp[8] = *(const uint4*)&vsrc[8];
#pragma unroll
    for (int i = 0; i < 16; ++i) Vt[ds0 + i][key] = tmp[i];
  }

  const int lane = tid & 63, w = tid >> 6;
  const int quad = lane >> 4, l16 = lane & 15;

  // Q A-fragments (rows w*16+l16)
  const ushort_t* qsrc = qb + (size_t)(b * 64 + w * 16 + l16) * DM + h * HD + quad * 8;
  bf16x8 aq0 = *(const bf16x8*)&qsrc[0];
  bf16x8 aq1 = *(const bf16x8*)&qsrc[32];

  // S = Q K^T
  f32x4 acc[4] = {};
#pragma unroll
  for (int nt = 0; nt < 4; ++nt) {
    const ushort_t* ksrc = kv + (size_t)(b * SEQ + c0 + nt * 16 + l16) * NKV + h * HD + quad * 8;
    bf16x8 bk0 = *(const bf16x8*)&ksrc[0];
    bf16x8 bk1 = *(const bf16x8*)&ksrc[32];
    acc[nt] = __builtin_amdgcn_mfma_f32_16x16x32_bf16(aq0, bk0, acc[nt], 0, 0, 0);
    acc[nt] = __builtin_amdgcn_mfma_f32_16x16x32_bf16(aq1, bk1, acc[nt], 0, 0, 0);
  }

  // per-chunk softmax (row stats across l16 lanes of same quad)
  float p[4][4];   // [nt][reg]
  float mrow[4], lrow[4];
#pragma unroll
  for (int r = 0; r < 4; ++r) {
    const int q = w * 16 + quad * 4 + r;
    const int t = tS[q];
    float mx = -1e30f;
#pragma unroll
    for (int nt = 0; nt < 4; ++nt) {
      float s = acc[nt][r] * 0.125f;            // 1/sqrt(64)
      if (c0 + nt * 16 + l16 > t) s = -1e30f;   // causal + invalid rows
      p[nt][r] = s;
      mx = fmaxf(mx, s);
    }
#pragma unroll
    for (int off = 1; off < 16; off <<= 1) mx = fmaxf(mx, __shfl_xor(mx, off));
    float sum = 0.f;
#pragma unroll
    for (int nt = 0; nt < 4; ++nt) {
      float pv = __expf(p[nt][r] - mx);
      p[nt][r] = pv;
      sum += pv;
    }
#pragma unroll
    for (int off = 1; off < 16; off <<= 1) sum += __shfl_xor(sum, off);
    mrow[r] = mx; lrow[r] = sum;
  }

  const size_t pbase = ((size_t)(b * NH + h) * NCHUNK + c) * 64;
  if (l16 == 0) {
#pragma unroll
    for (int r = 0; r < 4; ++r) {
      const int q = w * 16 + quad * 4 + r;
      m_part[pbase + q] = mrow[r];
      l_part[pbase + q] = lrow[r];
    }
  }

  // P -> LDS (A-layout source)
#pragma unroll
  for (int r = 0; r < 4; ++r)
#pragma unroll
    for (int nt = 0; nt < 4; ++nt)
      Ps[w][quad * 4 + r][nt * 16 + l16] = f2bf(p[nt][r]);
  __syncthreads();

  // O = P V
  bf16x8 ap0 = *(const bf16x8*)&Ps[w][l16][quad * 8];
  bf16x8 ap1 = *(const bf16x8*)&Ps[w][l16][32 + quad * 8];
  f32x4 acc2[4] = {};
#pragma unroll
  for (int nt = 0; nt < 4; ++nt) {
    bf16x8 bv0 = *(const bf16x8*)&Vt[nt * 16 + l16][quad * 8];
    bf16x8 bv1 = *(const bf16x8*)&Vt[nt * 16 + l16][32 + quad * 8];
    acc2[nt] = __builtin_amdgcn_mfma_f32_16x16x32_bf16(ap0, bv0, acc2[nt], 0, 0, 0);
    acc2[nt] = __builtin_amdgcn_mfma_f32_16x16x32_bf16(ap1, bv1, acc2[nt], 0, 0, 0);
  }
  float* obp = o_part + pbase * 64;
#pragma unroll
  for (int nt = 0; nt < 4; ++nt)
#pragma unroll
    for (int r = 0; r < 4; ++r)
      obp[(w * 16 + quad * 4 + r) * 64 + nt * 16 + l16] = acc2[nt][r];
}

// ---------------------------------------------------------------------------
// combine partials: grid (4 rowgroups, 12 h, 2 b), 256 thr
// ---------------------------------------------------------------------------
__global__ __launch_bounds__(256) void attn_combine_kernel(
    const float* __restrict__ m_part, const float* __restrict__ l_part,
    const float* __restrict__ o_part, const int* __restrict__ idx,
    float* __restrict__ ctx_rows) {
  __shared__ float wgt[NCHUNK][16];
  __shared__ float linv[16];
  __shared__ int ncS[16];
  const int rg = blockIdx.x, h = blockIdx.y, b = blockIdx.z;
  const int tid = threadIdx.x;
  const size_t base = (size_t)(b * NH + h) * NCHUNK * 64;
  if (tid < 16) {
    const int q = rg * 16 + tid;
    float L = 0.f; int nc = 0;
    if (q < KSEL) {
      const int t = idx[b * KSEL + q];
      nc = (t >> 6) + 1;
      float M = -1e30f;
      for (int cc = 0; cc < nc; ++cc)
        M = fmaxf(M, m_part[base + cc * 64 + q]);
      for (int cc = 0; cc < nc; ++cc) {
        float wv = __expf(m_part[base + cc * 64 + q] - M);
        wgt[cc][tid] = wv;
        L += wv * l_part[base + cc * 64 + q];
      }
    }
    ncS[tid] = nc;
    linv[tid] = (L > 0.f) ? 1.0f / L : 0.f;
  }
  __syncthreads();
  const int rl = tid >> 4;
  const int d4 = (tid & 15) * 4;
  const int q = rg * 16 + rl;
  if (q >= KSEL) return;
  const int nc = ncS[rl];
  float4 a = {0.f, 0.f, 0.f, 0.f};
  const float* obp = o_part + base * 64 + (size_t)q * 64 + d4;
  for (int cc = 0; cc < nc; ++cc) {
    const float wv = wgt[cc][rl];
    const float4 ov = *(const float4*)&obp[(size_t)cc * 4096];
    a.x += wv * ov.x; a.y += wv * ov.y; a.z += wv * ov.z; a.w += wv * ov.w;
  }
  const float li = linv[rl];
  float4 o;
  o.x = a.x * li; o.y = a.y * li; o.z = a.z * li; o.w = a.w * li;
  *(float4*)&ctx_rows[((size_t)(b * KSEL + q) * NH + h) * HD + d4] = o;
}

// ---------------------------------------------------------------------------
// out-proj + gate + scatter-add into y (y already = x)
// ---------------------------------------------------------------------------
__global__ __launch_bounds__(256) void outproj_kernel(
    const float* __restrict__ ctx_rows, const float* __restrict__ Wo,
    const float* __restrict__ ob, const int* __restrict__ idx,
    const float* __restrict__ sel, float* __restrict__ y) {
  __shared__ float cs[DM];
  const int row = blockIdx.x;           // 0..91
  const int b = row / KSEL;
  const int t = idx[row];
  const int tid = threadIdx.x;
  for (int i = tid; i < DM; i += 256) cs[i] = ctx_rows[(size_t)row * DM + i];
  __syncthreads();
  float a0 = 0.f, a1 = 0.f, a2 = 0.f;
  for (int k = 0; k < DM; ++k) {
    float c = cs[k];
    const float* wr = &Wo[(size_t)k * DM];
    a0 += c * wr[tid];
    a1 += c * wr[tid + 256];
    a2 += c * wr[tid + 512];
  }
  const float sv = sel[b * SEQ + t];
  float* yr = y + (size_t)(b * SEQ + t) * DM;
  yr[tid      ] += (a0 + ob[tid      ]) * sv;
  yr[tid + 256] += (a1 + ob[tid + 256]) * sv;
  yr[tid + 512] += (a2 + ob[tid + 512]) * sv;
}

// ---------------------------------------------------------------------------
extern "C" void kernel_launch(void* const* d_in, const int* in_sizes, int n_in,
                              void* d_out, int out_size, void* d_ws, size_t ws_size,
                              hipStream_t stream) {
  const float* x      = (const float*)d_in[0];
  const float* Wqkv_w = (const float*)d_in[1];
  const float* Wqkv_b = (const float*)d_in[2];
  const float* sel_w  = (const float*)d_in[3];
  const float* sel_b  = (const float*)d_in[4];
  const float* out_w  = (const float*)d_in[5];
  const float* out_b  = (const float*)d_in[6];
  const float* temp   = (const float*)d_in[7];
  float* y = (float*)d_out;

  // workspace layout (bytes, all 16B aligned)
  char* wsb = (char*)d_ws;
  ushort_t* kv     = (ushort_t*)wsb;                      wsb += (size_t)BATCH * SEQ * NKV * 2;   // 12.58 MB
  float*    o_part = (float*)wsb;                         wsb += (size_t)24 * NCHUNK * 64 * 64 * 4; // 12.58 MB
  float*    m_part = (float*)wsb;                         wsb += (size_t)24 * NCHUNK * 64 * 4;
  float*    l_part = (float*)wsb;                         wsb += (size_t)24 * NCHUNK * 64 * 4;
  float*    sel    = (float*)wsb;                         wsb += (size_t)BATCH * SEQ * 4;
  int*      idx    = (int*)wsb;                           wsb += 128 * 4;
  float*    ctx    = (float*)wsb;                         wsb += (size_t)NROW * DM * 4;
  ushort_t* qb     = (ushort_t*)wsb;                      wsb += (size_t)BATCH * 64 * DM * 2;
  ushort_t* Xbf    = (ushort_t*)wsb;                      wsb += (size_t)BATCH * SEQ * DM * 2;
  ushort_t* Wt     = (ushort_t*)wsb;                      wsb += (size_t)NKV * DM * 2;

  prep_kernel<<<dim3(8320), 256, 0, stream>>>(x, Wqkv_w, sel_w, sel_b, temp, Xbf, Wt, sel, y);
  topk_kernel<<<dim3(BATCH), 64, 0, stream>>>(sel, idx);
  kv_gemm<<<dim3(NKV / 128, BATCH * SEQ / 128), 256, 0, stream>>>(Xbf, Wt, Wqkv_b + DM, kv);
  qrows_kernel<<<dim3(BATCH * 64), 256, 0, stream>>>(x, Wqkv_w, Wqkv_b, idx, qb);
  attn_chunk_kernel<<<dim3(NCHUNK, NH, BATCH), 256, 0, stream>>>(kv, qb, idx, m_part, l_part, o_part);
  attn_combine_kernel<<<dim3(4, NH, BATCH), 256, 0, stream>>>(m_part, l_part, o_part, idx, ctx);
  outproj_kernel<<<dim3(NROW), 256, 0, stream>>>(ctx, out_w, out_b, idx, sel, y);
}

// Round 4
// 160.352 us; speedup vs baseline: 3.0876x; 1.8036x over previous
//
#include <hip/hip_runtime.h>
#include <hip/hip_bf16.h>
#include <cstddef>

// Problem constants
#define BATCH 2
#define SEQ   2048
#define DM    768
#define NH    12
#define HD    64
#define N3    2304      // 3*DM
#define NKV   1536      // 2*DM (K,V cols)
#define KSEL  46        // ceil(sqrt(2048))
#define NROW  (BATCH*KSEL)  // 92
#define NCHUNK 32       // 2048/64

typedef unsigned short ushort_t;
typedef __attribute__((ext_vector_type(8))) short bf16x8;
typedef __attribute__((ext_vector_type(4))) float f32x4;

__device__ __forceinline__ ushort_t f2bf(float f) {
  union { __hip_bfloat16 h; ushort_t u; } cv;
  cv.h = __float2bfloat16(f);
  return cv.u;
}
__device__ __forceinline__ float bf2f(ushort_t u) {
  union { unsigned int i; float f; } cv;
  cv.i = ((unsigned int)u) << 16;
  return cv.f;
}

#define GLD16(g, l)                                                         \
  __builtin_amdgcn_global_load_lds(                                         \
      (const __attribute__((address_space(1))) void*)(g),                   \
      (__attribute__((address_space(3))) void*)(l), 16, 0, 0)

// ---------------------------------------------------------------------------
// prep: fused cast_x (3072) + full-Wqkv transpose (1728) + WoT (576)
//       + sel (1024) + copy y=x (3072).  Total 9472 blocks.
// ---------------------------------------------------------------------------
__global__ __launch_bounds__(256) void prep_kernel(
    const float* __restrict__ x, const float* __restrict__ W,
    const float* __restrict__ Wo,
    const float* __restrict__ sel_w, const float* __restrict__ sel_b,
    const float* __restrict__ temp,
    ushort_t* __restrict__ xb, ushort_t* __restrict__ Wt,
    ushort_t* __restrict__ WoT,
    float* __restrict__ sel, float* __restrict__ y) {
  const int bx = blockIdx.x;
  const int tid = threadIdx.x;
  if (bx < 3072) {
    // cast x -> bf16
    int i = bx * 256 + tid;
    float4 f = ((const float4*)x)[i];
    ushort4 o;
    o.x = f2bf(f.x); o.y = f2bf(f.y); o.z = f2bf(f.z); o.w = f2bf(f.w);
    ((ushort4*)xb)[i] = o;
  } else if (bx < 4800) {
    // Wt[n][k] = bf16(W[k][n]), all 2304 cols; 32x32 tiles
    __shared__ float tile[32][33];
    const int bx2 = bx - 3072;
    const int n0 = (bx2 % 72) * 32, k0 = (bx2 / 72) * 32;
    const int r = tid >> 3, c4 = (tid & 7) * 4;
    float4 f = *(const float4*)&W[(size_t)(k0 + r) * N3 + n0 + c4];
    tile[r][c4] = f.x; tile[r][c4 + 1] = f.y; tile[r][c4 + 2] = f.z; tile[r][c4 + 3] = f.w;
    __syncthreads();
    ushort4 o;
    o.x = f2bf(tile[c4 + 0][r]);
    o.y = f2bf(tile[c4 + 1][r]);
    o.z = f2bf(tile[c4 + 2][r]);
    o.w = f2bf(tile[c4 + 3][r]);
    *(ushort4*)&Wt[(size_t)(n0 + r) * DM + k0 + c4] = o;
  } else if (bx < 5376) {
    // WoT[n][k] = bf16(Wo[k][n]); 32x32 tiles
    __shared__ float tile2[32][33];
    const int bx3 = bx - 4800;
    const int n0 = (bx3 % 24) * 32, k0 = (bx3 / 24) * 32;
    const int r = tid >> 3, c4 = (tid & 7) * 4;
    float4 f = *(const float4*)&Wo[(size_t)(k0 + r) * DM + n0 + c4];
    tile2[r][c4] = f.x; tile2[r][c4 + 1] = f.y; tile2[r][c4 + 2] = f.z; tile2[r][c4 + 3] = f.w;
    __syncthreads();
    ushort4 o;
    o.x = f2bf(tile2[c4 + 0][r]);
    o.y = f2bf(tile2[c4 + 1][r]);
    o.z = f2bf(tile2[c4 + 2][r]);
    o.w = f2bf(tile2[c4 + 3][r]);
    *(ushort4*)&WoT[(size_t)(n0 + r) * DM + k0 + c4] = o;
  } else if (bx < 6400) {
    // selection prob (fp32, bit-identical across rounds so topk set stable)
    int wave = tid >> 6, lane = tid & 63;
    int row = (bx - 5376) * 4 + wave;
    const float* xr = x + (size_t)row * DM;
    float a0 = 0.f, a1 = 0.f;
    for (int i = 0; i < DM / 64; ++i) {
      int k = lane + 64 * i;
      float xv = xr[k];
      a0 += xv * sel_w[2 * k];
      a1 += xv * sel_w[2 * k + 1];
    }
    for (int off = 32; off; off >>= 1) {
      a0 += __shfl_xor(a0, off);
      a1 += __shfl_xor(a1, off);
    }
    if (lane == 0) {
      float t = temp[0];
      float l0 = (a0 + sel_b[0]) / t;
      float l1 = (a1 + sel_b[1]) / t;
      sel[row] = 1.0f / (1.0f + expf(l0 - l1));
    }
  } else {
    // y = x
    int i = (bx - 6400) * 256 + tid;
    ((float4*)y)[i] = ((const float4*)x)[i];
  }
}

// ---------------------------------------------------------------------------
// top-46 per batch via radix select on float bits (sel >= 0 -> monotone).
// Order of emitted indices is irrelevant (scatter-add commutes); tie-break
// keeps lowest indices, matching jax.lax.top_k's selected SET.
// grid 2 x 256.  Writes idx[b*46+j] and padded idxp[b*64+j] (0-filled).
// ---------------------------------------------------------------------------
__global__ __launch_bounds__(256) void topk_kernel(
    const float* __restrict__ sel, int* __restrict__ idx,
    int* __restrict__ idxp) {
  __shared__ unsigned int hist[256];
  __shared__ unsigned int cum[256];
  __shared__ int sh_b;
  __shared__ int c_gt, c_eq;
  __shared__ int tmp_gt[KSEL];
  __shared__ int eqlist[256];
  const int b = blockIdx.x, tid = threadIdx.x;

  unsigned int key[8];
  int  kidx[8];
#pragma unroll
  for (int e = 0; e < 8; ++e) {
    int i = e * 256 + tid;
    kidx[e] = i;
    key[e] = __float_as_uint(sel[b * SEQ + i]);
  }
  unsigned int prefix = 0, mask = 0;
  int r = KSEL;
#pragma unroll
  for (int p = 3; p >= 0; --p) {
    const int shift = 8 * p;
    hist[tid] = 0;
    __syncthreads();
#pragma unroll
    for (int e = 0; e < 8; ++e)
      if ((key[e] & mask) == prefix)
        atomicAdd(&hist[(key[e] >> shift) & 255], 1u);
    __syncthreads();
    cum[tid] = hist[tid];
    __syncthreads();
    for (int d = 1; d < 256; d <<= 1) {
      unsigned int t = (tid + d < 256) ? cum[tid + d] : 0;
      __syncthreads();
      cum[tid] += t;
      __syncthreads();
    }
    if (cum[tid] >= (unsigned int)r && (tid == 255 || cum[tid + 1] < (unsigned int)r))
      sh_b = tid;
    __syncthreads();
    const int bsel = sh_b;
    r -= (bsel == 255) ? 0 : (int)cum[bsel + 1];
    prefix |= ((unsigned int)bsel) << shift;
    mask |= 0xFFu << shift;
    __syncthreads();
  }
  // T = prefix; select all > T, plus r lowest-index == T
  if (tid == 0) { c_gt = 0; c_eq = 0; }
  __syncthreads();
#pragma unroll
  for (int e = 0; e < 8; ++e) {
    if (key[e] > prefix) {
      int pos = atomicAdd(&c_gt, 1);
      tmp_gt[pos] = kidx[e];
    } else if (key[e] == prefix) {
      int pos = atomicAdd(&c_eq, 1);
      if (pos < 256) eqlist[pos] = kidx[e];
    }
  }
  __syncthreads();
  if (tid == 0) {
    const int need = KSEL - c_gt;
    const int ec = (c_eq < 256) ? c_eq : 256;
    for (int a = 0; a < need; ++a) {       // selection of smallest indices
      int mb = a;
      for (int bb = a + 1; bb < ec; ++bb)
        if (eqlist[bb] < eqlist[mb]) mb = bb;
      int tv = eqlist[a]; eqlist[a] = eqlist[mb]; eqlist[mb] = tv;
    }
  }
  __syncthreads();
  if (tid < 64) {
    if (tid < KSEL) {
      int t = (tid < c_gt) ? tmp_gt[tid] : eqlist[tid - c_gt];
      idx[b * KSEL + tid] = t;
      idxp[b * 64 + tid] = t;
    } else {
      idxp[b * 64 + tid] = 0;
    }
  }
}

// ---------------------------------------------------------------------------
// Fused GEMM (bf16 MFMA), 390 blocks:
//   blocks [0,384): kv[4096,1536] = Xbf @ Wt[768:2304]^T + bias  (bf16 out)
//   blocks [384,390): qb[128,768] = Xbf[gathered rows] @ Wt[0:768]^T + bias
// 128x128 tile, BK=32, 4 waves each 64x64.
// ---------------------------------------------------------------------------
__global__ __launch_bounds__(256) void gemm_kernel(
    const ushort_t* __restrict__ Xbf,   // [4096][768]
    const ushort_t* __restrict__ Wt,    // [2304][768]
    const float* __restrict__ bias,     // 2304
    const int* __restrict__ idxp,       // [128] padded selected rows
    ushort_t* __restrict__ Ckv,         // [4096][1536] bf16
    ushort_t* __restrict__ qb) {        // [128][768] bf16
  __shared__ ushort_t As[128 * 32];
  __shared__ ushort_t Bs[128 * 32];
  const int bid = blockIdx.x;
  const int tid = threadIdx.x;
  const int lane = tid & 63, w = tid >> 6;
  const int wr = w >> 1, wc = w & 1;
  const int quad = lane >> 4, l16 = lane & 15;
  const int ci0 = tid;
  const int ci1 = 256 + tid;
  const bool isQ = (bid >= 384);
  int m0, n0;
  size_t ga0, ga1;  // element offsets of this thread's A-staging rows
  if (isQ) {
    m0 = 0;
    n0 = (bid - 384) * 128;
    const int r0 = ci0 >> 2, r1 = ci1 >> 2;
    ga0 = (size_t)((r0 >> 6) * SEQ + idxp[r0]) * DM;
    ga1 = (size_t)((r1 >> 6) * SEQ + idxp[r1]) * DM;
  } else {
    m0 = (bid / 12) * 128;
    n0 = 768 + (bid % 12) * 128;
    ga0 = (size_t)(m0 + (ci0 >> 2)) * DM;
    ga1 = (size_t)(m0 + (ci1 >> 2)) * DM;
  }
  const size_t gb0 = (size_t)(n0 + (ci0 >> 2)) * DM;
  const size_t gb1 = (size_t)(n0 + (ci1 >> 2)) * DM;
  const int ka0 = (ci0 & 3) * 8, ka1 = (ci1 & 3) * 8;

  f32x4 acc[4][4] = {};
  for (int k0 = 0; k0 < DM; k0 += 32) {
    GLD16(Xbf + ga0 + k0 + ka0, &As[(w * 64) * 8]);
    GLD16(Xbf + ga1 + k0 + ka1, &As[(256 + w * 64) * 8]);
    GLD16(Wt + gb0 + k0 + ka0, &Bs[(w * 64) * 8]);
    GLD16(Wt + gb1 + k0 + ka1, &Bs[(256 + w * 64) * 8]);
    __syncthreads();
    bf16x8 af[4], bfr[4];
#pragma unroll
    for (int i = 0; i < 4; ++i)
      af[i] = *(const bf16x8*)&As[(wr * 64 + i * 16 + l16) * 32 + quad * 8];
#pragma unroll
    for (int j = 0; j < 4; ++j)
      bfr[j] = *(const bf16x8*)&Bs[(wc * 64 + j * 16 + l16) * 32 + quad * 8];
#pragma unroll
    for (int i = 0; i < 4; ++i)
#pragma unroll
      for (int j = 0; j < 4; ++j)
        acc[i][j] = __builtin_amdgcn_mfma_f32_16x16x32_bf16(af[i], bfr[j], acc[i][j], 0, 0, 0);
    __syncthreads();
  }
#pragma unroll
  for (int i = 0; i < 4; ++i) {
    const int row_base = wr * 64 + i * 16 + quad * 4;
#pragma unroll
    for (int j = 0; j < 4; ++j) {
      const int col = n0 + wc * 64 + j * 16 + l16;
      const float bv = bias[col];
      if (isQ) {
#pragma unroll
        for (int r = 0; r < 4; ++r)
          qb[(size_t)(row_base + r) * DM + col] = f2bf(acc[i][j][r] + bv);
      } else {
#pragma unroll
        for (int r = 0; r < 4; ++r)
          Ckv[(size_t)(m0 + row_base + r) * NKV + (col - 768)] = f2bf(acc[i][j][r] + bv);
      }
    }
  }
}

// ---------------------------------------------------------------------------
// attention chunk kernel: grid (32 chunks, 12 h, 2 b), 256 thr = 4 waves.
// S[64x64] via MFMA, per-chunk softmax, PV via MFMA, bf16 partial O.
// ---------------------------------------------------------------------------
__global__ __launch_bounds__(256) void attn_chunk_kernel(
    const ushort_t* __restrict__ kv,   // [4096][1536] bf16
    const ushort_t* __restrict__ qb,   // [128][768] bf16
    const int* __restrict__ idx,
    float* __restrict__ m_part, float* __restrict__ l_part,
    ushort_t* __restrict__ o_part) {
  __shared__ __align__(16) ushort_t Vt[64][72];
  __shared__ __align__(16) ushort_t Ps[4][16][72];
  __shared__ int tS[64];
  __shared__ int tmaxS;
  const int tid = threadIdx.x;
  const int c = blockIdx.x, h = blockIdx.y, b = blockIdx.z;
  const int c0 = c * 64;
  if (tid < 64) {
    int t = (tid < KSEL) ? idx[b * KSEL + tid] : -1;
    tS[tid] = t;
    int tm = t;
    for (int off = 32; off; off >>= 1) tm = max(tm, __shfl_xor(tm, off));
    if (tid == 0) tmaxS = tm;
  }
  __syncthreads();
  if (c0 > tmaxS) return;   // uniform across block

  // stage V transposed: Vt[d][key]
  {
    const int key = tid >> 2, ds0 = (tid & 3) * 16;
    const ushort_t* vsrc = kv + (size_t)(b * SEQ + c0 + key) * NKV + DM + h * HD + ds0;
    ushort_t tmp[16];
    *(uint4*)&tmp[0] = *(const uint4*)&vsrc[0];
    *(uint4*)&tmp[8] = *(const uint4*)&vsrc[8];
#pragma unroll
    for (int i = 0; i < 16; ++i) Vt[ds0 + i][key] = tmp[i];
  }

  const int lane = tid & 63, w = tid >> 6;
  const int quad = lane >> 4, l16 = lane & 15;

  const ushort_t* qsrc = qb + (size_t)(b * 64 + w * 16 + l16) * DM + h * HD + quad * 8;
  bf16x8 aq0 = *(const bf16x8*)&qsrc[0];
  bf16x8 aq1 = *(const bf16x8*)&qsrc[32];

  // S = Q K^T
  f32x4 acc[4] = {};
#pragma unroll
  for (int nt = 0; nt < 4; ++nt) {
    const ushort_t* ksrc = kv + (size_t)(b * SEQ + c0 + nt * 16 + l16) * NKV + h * HD + quad * 8;
    bf16x8 bk0 = *(const bf16x8*)&ksrc[0];
    bf16x8 bk1 = *(const bf16x8*)&ksrc[32];
    acc[nt] = __builtin_amdgcn_mfma_f32_16x16x32_bf16(aq0, bk0, acc[nt], 0, 0, 0);
    acc[nt] = __builtin_amdgcn_mfma_f32_16x16x32_bf16(aq1, bk1, acc[nt], 0, 0, 0);
  }

  // per-chunk softmax
  float p[4][4];
  float mrow[4], lrow[4];
#pragma unroll
  for (int r = 0; r < 4; ++r) {
    const int q = w * 16 + quad * 4 + r;
    const int t = tS[q];
    float mx = -1e30f;
#pragma unroll
    for (int nt = 0; nt < 4; ++nt) {
      float s = acc[nt][r] * 0.125f;
      if (c0 + nt * 16 + l16 > t) s = -1e30f;
      p[nt][r] = s;
      mx = fmaxf(mx, s);
    }
#pragma unroll
    for (int off = 1; off < 16; off <<= 1) mx = fmaxf(mx, __shfl_xor(mx, off));
    float sum = 0.f;
#pragma unroll
    for (int nt = 0; nt < 4; ++nt) {
      float pv = __expf(p[nt][r] - mx);
      p[nt][r] = pv;
      sum += pv;
    }
#pragma unroll
    for (int off = 1; off < 16; off <<= 1) sum += __shfl_xor(sum, off);
    mrow[r] = mx; lrow[r] = sum;
  }

  const size_t pbase = ((size_t)(b * NH + h) * NCHUNK + c) * 64;
  if (l16 == 0) {
#pragma unroll
    for (int r = 0; r < 4; ++r) {
      const int q = w * 16 + quad * 4 + r;
      m_part[pbase + q] = mrow[r];
      l_part[pbase + q] = lrow[r];
    }
  }

  // P -> LDS (A-layout source)
#pragma unroll
  for (int r = 0; r < 4; ++r)
#pragma unroll
    for (int nt = 0; nt < 4; ++nt)
      Ps[w][quad * 4 + r][nt * 16 + l16] = f2bf(p[nt][r]);
  __syncthreads();

  // O = P V
  bf16x8 ap0 = *(const bf16x8*)&Ps[w][l16][quad * 8];
  bf16x8 ap1 = *(const bf16x8*)&Ps[w][l16][32 + quad * 8];
  f32x4 acc2[4] = {};
#pragma unroll
  for (int nt = 0; nt < 4; ++nt) {
    bf16x8 bv0 = *(const bf16x8*)&Vt[nt * 16 + l16][quad * 8];
    bf16x8 bv1 = *(const bf16x8*)&Vt[nt * 16 + l16][32 + quad * 8];
    acc2[nt] = __builtin_amdgcn_mfma_f32_16x16x32_bf16(ap0, bv0, acc2[nt], 0, 0, 0);
    acc2[nt] = __builtin_amdgcn_mfma_f32_16x16x32_bf16(ap1, bv1, acc2[nt], 0, 0, 0);
  }
  ushort_t* obp = o_part + pbase * 64;
#pragma unroll
  for (int nt = 0; nt < 4; ++nt)
#pragma unroll
    for (int r = 0; r < 4; ++r)
      obp[(w * 16 + quad * 4 + r) * 64 + nt * 16 + l16] = f2bf(acc2[nt][r]);
}

// ---------------------------------------------------------------------------
// combine partials -> ctx (bf16, padded [128][768]): grid (3, 12, 2)
// ---------------------------------------------------------------------------
__global__ __launch_bounds__(256) void attn_combine_kernel(
    const float* __restrict__ m_part, const float* __restrict__ l_part,
    const ushort_t* __restrict__ o_part, const int* __restrict__ idx,
    ushort_t* __restrict__ ctx_bf) {
  __shared__ float wgt[NCHUNK][16];
  __shared__ float linv[16];
  __shared__ int ncS[16];
  const int rg = blockIdx.x, h = blockIdx.y, b = blockIdx.z;
  const int tid = threadIdx.x;
  const size_t base = (size_t)(b * NH + h) * NCHUNK * 64;
  if (tid < 16) {
    const int q = rg * 16 + tid;
    float L = 0.f; int nc = 0;
    if (q < KSEL) {
      const int t = idx[b * KSEL + q];
      nc = (t >> 6) + 1;
      float M = -1e30f;
      for (int cc = 0; cc < nc; ++cc)
        M = fmaxf(M, m_part[base + cc * 64 + q]);
      for (int cc = 0; cc < nc; ++cc) {
        float wv = __expf(m_part[base + cc * 64 + q] - M);
        wgt[cc][tid] = wv;
        L += wv * l_part[base + cc * 64 + q];
      }
    }
    ncS[tid] = nc;
    linv[tid] = (L > 0.f) ? 1.0f / L : 0.f;
  }
  __syncthreads();
  const int rl = tid >> 4;
  const int d4 = (tid & 15) * 4;
  const int q = rg * 16 + rl;
  if (q >= KSEL) return;
  const int nc = ncS[rl];
  float4 a = {0.f, 0.f, 0.f, 0.f};
  const ushort_t* obp = o_part + base * 64 + (size_t)q * 64 + d4;
  for (int cc = 0; cc < nc; ++cc) {
    const float wv = wgt[cc][rl];
    const ushort4 ov = *(const ushort4*)&obp[(size_t)cc * 4096];
    a.x += wv * bf2f(ov.x); a.y += wv * bf2f(ov.y);
    a.z += wv * bf2f(ov.z); a.w += wv * bf2f(ov.w);
  }
  const float li = linv[rl];
  ushort4 o;
  o.x = f2bf(a.x * li); o.y = f2bf(a.y * li);
  o.z = f2bf(a.z * li); o.w = f2bf(a.w * li);
  *(ushort4*)&ctx_bf[(size_t)(b * 64 + q) * DM + h * HD + d4] = o;
}

// ---------------------------------------------------------------------------
// out-proj GEMM (bf16 MFMA, 6 blocks): gated = (ctx @ WoT^T + ob) * sel,
// scatter-added straight into y.  M=128 (92 valid), N=768, K=768.
// ---------------------------------------------------------------------------
__global__ __launch_bounds__(256) void outproj_kernel(
    const ushort_t* __restrict__ ctx_bf,  // [128][768]
    const ushort_t* __restrict__ WoT,     // [768][768]
    const float* __restrict__ ob, const int* __restrict__ idx,
    const float* __restrict__ sel, float* __restrict__ y) {
  __shared__ ushort_t As[128 * 32];
  __shared__ ushort_t Bs[128 * 32];
  const int tid = threadIdx.x;
  const int lane = tid & 63, w = tid >> 6;
  const int wr = w >> 1, wc = w & 1;
  const int n0 = blockIdx.x * 128;
  const int quad = lane >> 4, l16 = lane & 15;
  const int ci0 = tid;
  const int ci1 = 256 + tid;
  const size_t ga0 = (size_t)(ci0 >> 2) * DM;
  const size_t ga1 = (size_t)(ci1 >> 2) * DM;
  const size_t gb0 = (size_t)(n0 + (ci0 >> 2)) * DM;
  const size_t gb1 = (size_t)(n0 + (ci1 >> 2)) * DM;
  const int ka0 = (ci0 & 3) * 8, ka1 = (ci1 & 3) * 8;
  f32x4 acc[4][4] = {};
  for (int k0 = 0; k0 < DM; k0 += 32) {
    GLD16(ctx_bf + ga0 + k0 + ka0, &As[(w * 64) * 8]);
    GLD16(ctx_bf + ga1 + k0 + ka1, &As[(256 + w * 64) * 8]);
    GLD16(WoT + gb0 + k0 + ka0, &Bs[(w * 64) * 8]);
    GLD16(WoT + gb1 + k0 + ka1, &Bs[(256 + w * 64) * 8]);
    __syncthreads();
    bf16x8 af[4], bfr[4];
#pragma unroll
    for (int i = 0; i < 4; ++i)
      af[i] = *(const bf16x8*)&As[(wr * 64 + i * 16 + l16) * 32 + quad * 8];
#pragma unroll
    for (int j = 0; j < 4; ++j)
      bfr[j] = *(const bf16x8*)&Bs[(wc * 64 + j * 16 + l16) * 32 + quad * 8];
#pragma unroll
    for (int i = 0; i < 4; ++i)
#pragma unroll
      for (int j = 0; j < 4; ++j)
        acc[i][j] = __builtin_amdgcn_mfma_f32_16x16x32_bf16(af[i], bfr[j], acc[i][j], 0, 0, 0);
    __syncthreads();
  }
#pragma unroll
  for (int i = 0; i < 4; ++i) {
#pragma unroll
    for (int r = 0; r < 4; ++r) {
      const int row = wr * 64 + i * 16 + quad * 4 + r;
      const int b = row >> 6, jj = row & 63;
      if (jj >= KSEL) continue;
      const int t = idx[b * KSEL + jj];
      const float sv = sel[b * SEQ + t];
      float* yr = y + (size_t)(b * SEQ + t) * DM;
#pragma unroll
      for (int j = 0; j < 4; ++j) {
        const int col = n0 + wc * 64 + j * 16 + l16;
        yr[col] += (acc[i][j][r] + ob[col]) * sv;
      }
    }
  }
}

// ---------------------------------------------------------------------------
extern "C" void kernel_launch(void* const* d_in, const int* in_sizes, int n_in,
                              void* d_out, int out_size, void* d_ws, size_t ws_size,
                              hipStream_t stream) {
  const float* x      = (const float*)d_in[0];
  const float* Wqkv_w = (const float*)d_in[1];
  const float* Wqkv_b = (const float*)d_in[2];
  const float* sel_w  = (const float*)d_in[3];
  const float* sel_b  = (const float*)d_in[4];
  const float* out_w  = (const float*)d_in[5];
  const float* out_b  = (const float*)d_in[6];
  const float* temp   = (const float*)d_in[7];
  float* y = (float*)d_out;

  // workspace layout (bytes, all 16B aligned)
  char* wsb = (char*)d_ws;
  ushort_t* kv     = (ushort_t*)wsb;  wsb += (size_t)BATCH * SEQ * NKV * 2;        // 12.58 MB
  ushort_t* o_part = (ushort_t*)wsb;  wsb += (size_t)24 * NCHUNK * 64 * 64 * 2;    // 6.29 MB
  float*    m_part = (float*)wsb;     wsb += (size_t)24 * NCHUNK * 64 * 4;
  float*    l_part = (float*)wsb;     wsb += (size_t)24 * NCHUNK * 64 * 4;
  float*    sel    = (float*)wsb;     wsb += (size_t)BATCH * SEQ * 4;
  int*      idx    = (int*)wsb;       wsb += 128 * 4;
  int*      idxp   = (int*)wsb;       wsb += 128 * 4;
  ushort_t* ctx_bf = (ushort_t*)wsb;  wsb += (size_t)128 * DM * 2;
  ushort_t* qb     = (ushort_t*)wsb;  wsb += (size_t)128 * DM * 2;
  ushort_t* Xbf    = (ushort_t*)wsb;  wsb += (size_t)BATCH * SEQ * DM * 2;         // 6.29 MB
  ushort_t* Wt     = (ushort_t*)wsb;  wsb += (size_t)N3 * DM * 2;                  // 3.54 MB
  ushort_t* WoT    = (ushort_t*)wsb;  wsb += (size_t)DM * DM * 2;                  // 1.18 MB

  prep_kernel<<<dim3(9472), 256, 0, stream>>>(x, Wqkv_w, out_w, sel_w, sel_b, temp,
                                              Xbf, Wt, WoT, sel, y);
  topk_kernel<<<dim3(BATCH), 256, 0, stream>>>(sel, idx, idxp);
  gemm_kernel<<<dim3(390), 256, 0, stream>>>(Xbf, Wt, Wqkv_b, idxp, kv, qb);
  attn_chunk_kernel<<<dim3(NCHUNK, NH, BATCH), 256, 0, stream>>>(kv, qb, idx, m_part, l_part, o_part);
  attn_combine_kernel<<<dim3(3, NH, BATCH), 256, 0, stream>>>(m_part, l_part, o_part, idx, ctx_bf);
  outproj_kernel<<<dim3(6), 256, 0, stream>>>(ctx_bf, WoT, out_b, idx, sel, y);
}